// Round 12
// baseline (621.286 us; speedup 1.0000x reference)
//
#include <hip/hip_runtime.h>
#include <hip/hip_bf16.h>
#include <math.h>

#define N_NODES 20000
#define N_EDGES 480000
#define HIDDEN  128
#define ZDIM    384        // 2*HIDDEN + EDGE_FEAT
#define NOUT    256        // 2*HIDDEN
#define BN_EPS  1e-5f

#define LDA     392        // fallback kernel only
#define LDZ     264        // fallback kernel only

using bf16x8 = __attribute__((ext_vector_type(8))) short;
using f32x4  = __attribute__((ext_vector_type(4))) float;
using f32x16 = __attribute__((ext_vector_type(16))) float;
using s16x4  = __attribute__((ext_vector_type(4))) short;

struct f32x8 { float4 a, b; };

__device__ __forceinline__ unsigned short f2b(float f) {
    union { float f; unsigned u; } v; v.f = f;
    unsigned r = v.u + 0x7fffu + ((v.u >> 16) & 1u);   // RTNE
    return (unsigned short)(r >> 16);
}
__device__ __forceinline__ float bflo(unsigned u) {
    union { unsigned x; float f; } v; v.x = u << 16; return v.f;
}
__device__ __forceinline__ float bfhi(unsigned u) {
    union { unsigned x; float f; } v; v.x = u & 0xffff0000u; return v.f;
}
__device__ __forceinline__ float b2f(unsigned short s) {
    union { unsigned u; float f; } v; v.u = ((unsigned)s) << 16; return v.f;
}
__device__ __forceinline__ float sigmoid_(float x) {
    return 1.f / (1.f + __expf(-x));
}
__device__ __forceinline__ float softplus_(float x) {
    return fmaxf(x, 0.f) + __logf(1.f + __expf(-fabsf(x)));
}
__device__ __forceinline__ f32x8 ld8(const float* p) {
    f32x8 r; r.a = *(const float4*)p; r.b = *(const float4*)(p + 4); return r;
}
__device__ __forceinline__ bf16x8 cvt8(f32x8 v) {
    bf16x8 pk;
    pk[0] = (short)f2b(v.a.x); pk[1] = (short)f2b(v.a.y);
    pk[2] = (short)f2b(v.a.z); pk[3] = (short)f2b(v.a.w);
    pk[4] = (short)f2b(v.b.x); pk[5] = (short)f2b(v.b.y);
    pk[6] = (short)f2b(v.b.z); pk[7] = (short)f2b(v.b.w);
    return pk;
}

// ---- W [384][256] f32  ->  Wt [256][384] bf16 ----------------------------
__global__ void convW(const float* __restrict__ W, short* __restrict__ wt) {
    int n = blockIdx.x;
    for (int k = threadIdx.x; k < ZDIM; k += 256)
        wt[n * ZDIM + k] = (short)f2b(W[(size_t)k * NOUT + n]);
}

// ---- BN stats -> scale/shift ---------------------------------------------
__global__ void bn_finalize(const float* __restrict__ stats,
                            const float* __restrict__ gamma,
                            const float* __restrict__ beta,
                            float* __restrict__ scaleC,
                            float* __restrict__ shiftC) {
    int c = threadIdx.x;
    float s = 0.f, q = 0.f;
    for (int p = 0; p < 64; ++p) {
        s += stats[p * 512 + c];
        q += stats[p * 512 + 256 + c];
    }
    const float invE = 1.f / (float)N_EDGES;
    float m   = s * invE;                    // linear bias b cancels in BN
    float var = q * invE - m * m;
    float inv = rsqrtf(var + BN_EPS);
    float sc  = gamma[c] * inv;
    scaleC[c] = sc;
    shiftC[c] = beta[c] - m * sc;
}

// ---- counting sort of edges by dst ---------------------------------------
__global__ void hist_dst(const int* __restrict__ dst, int* __restrict__ counts) {
    int i = blockIdx.x * 256 + threadIdx.x;
    if (i < N_EDGES) atomicAdd(&counts[dst[i]], 1);
}

__global__ void scan_nodes(const int* __restrict__ counts, int* __restrict__ offs,
                           int* __restrict__ cursor) {
    __shared__ int part[1024];
    int t = threadIdx.x;
    int base = t * 20;
    int local[20]; int s = 0;
    #pragma unroll
    for (int k = 0; k < 20; ++k) {
        int idx = base + k;
        int v = (idx < N_NODES) ? counts[idx] : 0;
        local[k] = s; s += v;
    }
    part[t] = s; __syncthreads();
    for (int d = 1; d < 1024; d <<= 1) {
        int v = (t >= d) ? part[t - d] : 0;
        __syncthreads();
        part[t] += v;
        __syncthreads();
    }
    int pre = (t > 0) ? part[t - 1] : 0;
    #pragma unroll
    for (int k = 0; k < 20; ++k) {
        int idx = base + k;
        if (idx < N_NODES) { int o = pre + local[k]; offs[idx] = o; cursor[idx] = o; }
    }
}

// packed per-edge info: {src, dst, dst-sorted slot, 0}
__global__ void build_einfo(const int* __restrict__ src, const int* __restrict__ dst,
                            int* __restrict__ cursor, int4* __restrict__ einfo) {
    int i = blockIdx.x * 256 + threadIdx.x;
    if (i < N_EDGES) {
        int d = dst[i];
        int slot = atomicAdd(&cursor[d], 1);
        einfo[i] = make_int4(src[i], d, slot, 0);
    }
}

// ---- node projection -> bf16, col-pair-interleaved layout ----------------
// P1[i][w*64 + l*2 + n] = bf16(h[i] @ W1[:, w*64+n*32+l]); P2 likewise for W2.
__global__ __launch_bounds__(256)
void node_proj(const float* __restrict__ h, const short* __restrict__ wt,
               unsigned short* __restrict__ P1, unsigned short* __restrict__ P2) {
    const int tid  = threadIdx.x;
    const int lane = tid & 63;
    const int l31  = lane & 31;
    const int hi   = lane >> 5;
    const int w    = tid >> 6;
    const int rowBase = blockIdx.x * 64;
    const int colBase = blockIdx.y * 256 + w * 64;   // global col 0..511

    const float* pA[2];
    #pragma unroll
    for (int mi = 0; mi < 2; ++mi) {
        int row = rowBase + mi * 32 + l31;
        if (row > N_NODES - 1) row = N_NODES - 1;
        pA[mi] = h + (size_t)row * HIDDEN + hi * 8;
    }
    const short* pB[2];
    #pragma unroll
    for (int n = 0; n < 2; ++n) {
        int c = colBase + n * 32 + l31;
        pB[n] = wt + (size_t)(c & 255) * ZDIM + (c >> 8) * 128 + hi * 8;
    }

    f32x16 acc[2][2] = {};
    #pragma unroll
    for (int kk = 0; kk < 8; ++kk) {
        bf16x8 a[2], b[2];
        #pragma unroll
        for (int mi = 0; mi < 2; ++mi) a[mi] = cvt8(ld8(pA[mi] + kk * 16));
        #pragma unroll
        for (int n = 0; n < 2; ++n) b[n] = *(const bf16x8*)(pB[n] + kk * 16);
        #pragma unroll
        for (int mi = 0; mi < 2; ++mi)
            #pragma unroll
            for (int n = 0; n < 2; ++n)
                acc[mi][n] = __builtin_amdgcn_mfma_f32_32x32x16_bf16(
                                 a[mi], b[n], acc[mi][n], 0, 0, 0);
    }

    unsigned short* Pt = (blockIdx.y == 0) ? P1 : P2;
    const int pcol = (w * 64) + l31 * 2;             // in-table interleaved idx
    #pragma unroll
    for (int mi = 0; mi < 2; ++mi)
        #pragma unroll
        for (int r = 0; r < 16; ++r) {
            int row = rowBase + mi * 32 + 4 * hi + (r & 3) + 8 * (r >> 2);
            if (row < N_NODES) {
                unsigned pk = (unsigned)f2b(acc[mi][0][r]) |
                              ((unsigned)f2b(acc[mi][1][r]) << 16);
                *(unsigned*)&Pt[(size_t)row * 256 + pcol] = pk;
            }
        }
}

// ---- per-edge GEMM: e@W3 only; packed einfo; batched phases --------------
// z stored bf16, dst-sorted, SAME pair-interleaved layout as P tables.
__global__ __launch_bounds__(256, 3)
void edge_gemm3(const float* __restrict__ e, const int4* __restrict__ einfo,
                const short* __restrict__ wt,
                const unsigned short* __restrict__ P1,
                const unsigned short* __restrict__ P2,
                float* __restrict__ stats, short* __restrict__ zout) {
    const int tid  = threadIdx.x;
    const int lane = tid & 63;
    const int l31  = lane & 31;
    const int hi   = lane >> 5;
    const int w    = tid >> 6;
    const int rowBase = blockIdx.x * 64;
    const int colBase = w * 64;
    const int pcol = colBase + l31 * 2;      // interleaved pair index

    const float* pE[2];
    #pragma unroll
    for (int mi = 0; mi < 2; ++mi)
        pE[mi] = e + (size_t)(rowBase + mi * 32 + l31) * HIDDEN + hi * 8;
    const short* pB[2];
    #pragma unroll
    for (int n = 0; n < 2; ++n)
        pB[n] = wt + (size_t)(colBase + n * 32 + l31) * ZDIM + 256 + hi * 8;

    // ---- phase 1: A batch 1 + all B loads ----
    f32x8 t[2][4];
    #pragma unroll
    for (int mi = 0; mi < 2; ++mi)
        #pragma unroll
        for (int j = 0; j < 4; ++j) t[mi][j] = ld8(pE[mi] + j * 16);
    bf16x8 B[2][8];
    #pragma unroll
    for (int n = 0; n < 2; ++n)
        #pragma unroll
        for (int kk = 0; kk < 8; ++kk)
            B[n][kk] = *(const bf16x8*)(pB[n] + kk * 16);

    bf16x8 A0[2][4], A1[2][4];
    #pragma unroll
    for (int mi = 0; mi < 2; ++mi)
        #pragma unroll
        for (int j = 0; j < 4; ++j) A0[mi][j] = cvt8(t[mi][j]);
    #pragma unroll
    for (int mi = 0; mi < 2; ++mi)
        #pragma unroll
        for (int j = 0; j < 4; ++j) t[mi][j] = ld8(pE[mi] + 64 + j * 16);

    f32x16 acc[2][2] = {};
    #pragma unroll
    for (int kk = 0; kk < 4; ++kk)
        #pragma unroll
        for (int mi = 0; mi < 2; ++mi)
            #pragma unroll
            for (int n = 0; n < 2; ++n)
                acc[mi][n] = __builtin_amdgcn_mfma_f32_32x32x16_bf16(
                                 A0[mi][kk], B[n][kk], acc[mi][n], 0, 0, 0);
    #pragma unroll
    for (int mi = 0; mi < 2; ++mi)
        #pragma unroll
        for (int j = 0; j < 4; ++j) A1[mi][j] = cvt8(t[mi][j]);
    #pragma unroll
    for (int kk = 4; kk < 8; ++kk)
        #pragma unroll
        for (int mi = 0; mi < 2; ++mi)
            #pragma unroll
            for (int n = 0; n < 2; ++n)
                acc[mi][n] = __builtin_amdgcn_mfma_f32_32x32x16_bf16(
                                 A1[mi][kk - 4], B[n][kk], acc[mi][n], 0, 0, 0);

    // ---- phase 2: packed einfo loads + P gathers ----
    unsigned ps[2][16], pd[2][16];
    int slot[2][16];
    #pragma unroll
    for (int mi = 0; mi < 2; ++mi)
        #pragma unroll
        for (int r = 0; r < 16; ++r) {
            int rowL = mi * 32 + 4 * hi + (r & 3) + 8 * (r >> 2);
            int4 ei  = einfo[rowBase + rowL];
            slot[mi][r] = ei.z;
            ps[mi][r] = *(const unsigned*)&P1[(size_t)ei.x * 256 + pcol];
            pd[mi][r] = *(const unsigned*)&P2[(size_t)ei.y * 256 + pcol];
        }

    // ---- phase 3: consume (pure VALU) + interleaved u32 store ----
    float s2[2] = {0.f, 0.f}, q2[2] = {0.f, 0.f};
    #pragma unroll
    for (int mi = 0; mi < 2; ++mi)
        #pragma unroll
        for (int r = 0; r < 16; ++r) {
            float z0 = acc[mi][0][r] + bflo(ps[mi][r]) + bflo(pd[mi][r]);
            float z1 = acc[mi][1][r] + bfhi(ps[mi][r]) + bfhi(pd[mi][r]);
            s2[0] += z0; q2[0] += z0 * z0;
            s2[1] += z1; q2[1] += z1 * z1;
            unsigned pk = (unsigned)f2b(z0) | ((unsigned)f2b(z1) << 16);
            *(unsigned*)&zout[(size_t)slot[mi][r] * NOUT + pcol] = pk;
        }
    float* base = stats + (size_t)(blockIdx.x & 63) * 512;
    #pragma unroll
    for (int n = 0; n < 2; ++n) {
        float s = s2[n], q = q2[n];
        s += __shfl_xor(s, 32, 64);
        q += __shfl_xor(q, 32, 64);
        if (lane < 32) {
            int col = colBase + n * 32 + l31;
            atomicAdd(base + col, s);
            atomicAdd(base + 256 + col, q);
        }
    }
}

// ---- fallback (small ws): stage-all-LDS GEMM, stats or scatter -----------
template<int MODE>   // 1: stats only   2: normalize+gate+atomic scatter
__global__ __launch_bounds__(256)
void edge_gemm_fb(const float* __restrict__ h, const float* __restrict__ e,
                  const int* __restrict__ src, const int* __restrict__ dst,
                  const short* __restrict__ wt,
                  float* __restrict__ stats,
                  const float* __restrict__ scaleC, const float* __restrict__ shiftC,
                  float* __restrict__ agg) {
    const int tid  = threadIdx.x;
    const int bm   = blockIdx.x;
    const int rowBase = bm * 64;
    const int lane = tid & 63;
    const int brow = lane & 15;
    const int kgo  = (lane >> 4) * 8;
    const int wcol = (tid >> 6) * 64;

    __shared__ __align__(16) short lds[64 * LDA];

    #pragma unroll
    for (int j = 0; j < 12; ++j) {
        int u = tid + j * 256;
        int r = u / 48;
        int f0 = (u - r * 48) * 8;
        int row = rowBase + r;
        const float* p;
        if (f0 < 128)      p = h + (size_t)src[row] * HIDDEN + f0;
        else if (f0 < 256) p = h + (size_t)dst[row] * HIDDEN + (f0 - 128);
        else               p = e + (size_t)row * HIDDEN + (f0 - 256);
        *(bf16x8*)&lds[r * LDA + f0] = cvt8(ld8(p));
    }
    __syncthreads();

    const short* wB[4];
    #pragma unroll
    for (int n = 0; n < 4; ++n)
        wB[n] = wt + (size_t)(wcol + n * 16 + brow) * ZDIM + kgo;

    f32x4 acc[4][4] = {};
    #pragma unroll
    for (int kk = 0; kk < 12; ++kk) {
        bf16x8 aC[4], bC[4];
        #pragma unroll
        for (int m = 0; m < 4; ++m)
            aC[m] = *(const bf16x8*)&lds[(m * 16 + brow) * LDA + kk * 32 + kgo];
        #pragma unroll
        for (int n = 0; n < 4; ++n) bC[n] = *(const bf16x8*)(wB[n] + kk * 32);
        #pragma unroll
        for (int m = 0; m < 4; ++m)
            #pragma unroll
            for (int n = 0; n < 4; ++n)
                acc[m][n] = __builtin_amdgcn_mfma_f32_16x16x32_bf16(
                                aC[m], bC[n], acc[m][n], 0, 0, 0);
    }

    if (MODE == 1) {
        float* base = stats + (size_t)(bm & 63) * 512;
        #pragma unroll
        for (int n = 0; n < 4; ++n) {
            float s = 0.f, q = 0.f;
            #pragma unroll
            for (int m = 0; m < 4; ++m)
                #pragma unroll
                for (int r = 0; r < 4; ++r) {
                    float v = acc[m][n][r]; s += v; q += v * v;
                }
            s += __shfl_xor(s, 16, 64); s += __shfl_xor(s, 32, 64);
            q += __shfl_xor(q, 16, 64); q += __shfl_xor(q, 32, 64);
            if (lane < 16) {
                int col = wcol + n * 16 + lane;
                atomicAdd(base + col, s);
                atomicAdd(base + 256 + col, q);
            }
        }
    } else {
        float sc[4], sh[4];
        #pragma unroll
        for (int n = 0; n < 4; ++n) {
            int col = wcol + n * 16 + brow;
            sc[n] = scaleC[col]; sh[n] = shiftC[col];
        }
        __syncthreads();
        #pragma unroll
        for (int m = 0; m < 4; ++m) {
            int rowb = m * 16 + (lane >> 4) * 4;
            #pragma unroll
            for (int n = 0; n < 4; ++n) {
                int col = wcol + n * 16 + brow;
                #pragma unroll
                for (int r = 0; r < 4; ++r)
                    lds[(rowb + r) * LDZ + col] = (short)f2b(acc[m][n][r] * sc[n] + sh[n]);
            }
        }
        __syncthreads();
        const int c0 = (tid & 31) * 4;
        const int r0 = tid >> 5;
        #pragma unroll
        for (int rp = 0; rp < 8; ++rp) {
            int row = rp * 8 + r0;
            int d   = dst[rowBase + row];
            float* ap = agg + (size_t)d * HIDDEN + c0;
            s16x4 f4 = *(const s16x4*)&lds[row * LDZ + c0];
            s16x4 c4 = *(const s16x4*)&lds[row * LDZ + 128 + c0];
            #pragma unroll
            for (int j = 0; j < 4; ++j)
                atomicAdd(ap + j, sigmoid_(b2f((unsigned short)f4[j])) *
                                  softplus_(b2f((unsigned short)c4[j])));
        }
    }
}

// ---- per-node gather over pair-interleaved sorted z ----------------------
// position p = 64w + 2l + n  <->  col c = 64w + 32n + l
__global__ __launch_bounds__(256)
void node_gather(const short* __restrict__ z,
                 const int* __restrict__ offs, const int* __restrict__ counts,
                 const float* __restrict__ scaleC, const float* __restrict__ shiftC,
                 const float* __restrict__ h, float* __restrict__ out) {
    int node = blockIdx.x * 4 + (threadIdx.x >> 6);
    int lane = threadIdx.x & 63;
    int l32  = lane & 31;
    const int wq = l32 >> 4;                    // 0/1
    const int c0 = 64 * wq + 2 * (l32 & 15);    // cols: c0, c0+32, c0+1, c0+33

    float scF[4], shF[4], scS[4], shS[4];
    const int cmap[4] = {c0, c0 + 32, c0 + 1, c0 + 33};
    #pragma unroll
    for (int k = 0; k < 4; ++k) {
        scF[k] = scaleC[cmap[k]];       shF[k] = shiftC[cmap[k]];
        scS[k] = scaleC[128 + cmap[k]]; shS[k] = shiftC[128 + cmap[k]];
    }

    int s   = offs[node];
    int deg = counts[node];
    float a0 = 0.f, a1 = 0.f, a2 = 0.f, a3 = 0.f;
    const int po = 4 * l32;
    const int h2 = lane >> 5;                   // even/odd slot split

    for (int j = h2; j < deg; j += 8) {
        // 4 rows in flight: j, j+2, j+4, j+6
        const short* zP[4];
        bool has[4];
        #pragma unroll
        for (int k = 0; k < 4; ++k) {
            int jk = j + 2 * k;
            has[k] = (jk < deg);
            zP[k]  = z + (size_t)(s + (has[k] ? jk : j)) * NOUT;
        }
        uint2 fv[4], cv[4];
        #pragma unroll
        for (int k = 0; k < 4; ++k) {
            fv[k] = *(const uint2*)(zP[k] + po);
            cv[k] = *(const uint2*)(zP[k] + 128 + po);
        }
        #pragma unroll
        for (int k = 0; k < 4; ++k) {
            if (has[k]) {
                float f0 = bflo(fv[k].x) * scF[0] + shF[0];
                float f1 = bfhi(fv[k].x) * scF[1] + shF[1];
                float f2 = bflo(fv[k].y) * scF[2] + shF[2];
                float f3 = bfhi(fv[k].y) * scF[3] + shF[3];
                float g0 = bflo(cv[k].x) * scS[0] + shS[0];
                float g1 = bfhi(cv[k].x) * scS[1] + shS[1];
                float g2 = bflo(cv[k].y) * scS[2] + shS[2];
                float g3 = bfhi(cv[k].y) * scS[3] + shS[3];
                a0 += sigmoid_(f0) * softplus_(g0);
                a1 += sigmoid_(f1) * softplus_(g1);
                a2 += sigmoid_(f2) * softplus_(g2);
                a3 += sigmoid_(f3) * softplus_(g3);
            }
        }
    }
    a0 += __shfl_xor(a0, 32, 64);   // col c0
    a1 += __shfl_xor(a1, 32, 64);   // col c0+32
    a2 += __shfl_xor(a2, 32, 64);   // col c0+1
    a3 += __shfl_xor(a3, 32, 64);   // col c0+33

    if (lane < 32) {
        size_t o = (size_t)node * HIDDEN;
        float2 hA = *(const float2*)&h[o + c0];
        float2 hB = *(const float2*)&h[o + c0 + 32];
        float2 rA, rB;
        rA.x = softplus_(hA.x + a0);
        rA.y = softplus_(hA.y + a2);
        rB.x = softplus_(hB.x + a1);
        rB.y = softplus_(hB.y + a3);
        *(float2*)&out[o + c0]      = rA;
        *(float2*)&out[o + c0 + 32] = rB;
    }
}

// ---- fallback finalize ----------------------------------------------------
__global__ void node_finalize(const float* __restrict__ h, float* __restrict__ out) {
    int i = blockIdx.x * 256 + threadIdx.x;
    float4 hv = ((const float4*)h)[i];
    float4 av = ((float4*)out)[i];
    float4 r;
    r.x = softplus_(hv.x + av.x);
    r.y = softplus_(hv.y + av.y);
    r.z = softplus_(hv.z + av.z);
    r.w = softplus_(hv.w + av.w);
    ((float4*)out)[i] = r;
}

extern "C" void kernel_launch(void* const* d_in, const int* in_sizes, int n_in,
                              void* d_out, int out_size, void* d_ws, size_t ws_size,
                              hipStream_t stream) {
    const float* h     = (const float*)d_in[0];
    const float* e     = (const float*)d_in[1];
    const int*   srcp  = (const int*)d_in[2];
    const int*   dstp  = (const int*)d_in[3];
    const float* W     = (const float*)d_in[4];
    // d_in[5] = b : cancels through BatchNorm
    const float* gamma = (const float*)d_in[6];
    const float* beta  = (const float*)d_in[7];
    float* out = (float*)d_out;

    char*  ws     = (char*)d_ws;
    float* stats  = (float*)ws;                        // 131072 B
    float* scaleC = (float*)(ws + 131072);
    float* shiftC = (float*)(ws + 132096);
    short* wt     = (short*)(ws + 133120);             // 192 KB -> 329728
    int*   counts = (int*)(ws + 329728);
    int*   offs   = (int*)(ws + 409856);
    int*   cursor = (int*)(ws + 489984);
    int4*  einfo  = (int4*)(ws + 570112);              // 7.68 MB -> 8250112
    unsigned short* P1 = (unsigned short*)(ws + 8250112);   // 10.24 MB
    unsigned short* P2 = (unsigned short*)(ws + 18490112);  // 10.24 MB
    short* zbuf   = (short*)(ws + 28730112);           // 245.76 MB
    const size_t need = 28730112ull + (size_t)N_EDGES * NOUT * 2;

    hipMemsetAsync(stats, 0, 131072, stream);
    convW<<<NOUT, 256, 0, stream>>>(W, wt);

    if (ws_size >= need) {
        hipMemsetAsync(counts, 0, N_NODES * sizeof(int), stream);
        hist_dst<<<(N_EDGES + 255) / 256, 256, 0, stream>>>(dstp, counts);
        scan_nodes<<<1, 1024, 0, stream>>>(counts, offs, cursor);
        build_einfo<<<(N_EDGES + 255) / 256, 256, 0, stream>>>(srcp, dstp, cursor, einfo);

        node_proj<<<dim3((N_NODES + 63) / 64, 2), 256, 0, stream>>>(h, wt, P1, P2);
        edge_gemm3<<<N_EDGES / 64, 256, 0, stream>>>(e, einfo, wt, P1, P2,
                stats, zbuf);
        bn_finalize<<<1, 256, 0, stream>>>(stats, gamma, beta, scaleC, shiftC);
        node_gather<<<N_NODES / 4, 256, 0, stream>>>(zbuf, offs, counts,
                scaleC, shiftC, h, out);
    } else {
        hipMemsetAsync(out, 0, (size_t)N_NODES * HIDDEN * sizeof(float), stream);
        edge_gemm_fb<1><<<N_EDGES / 64, 256, 0, stream>>>(h, e, srcp, dstp, wt,
                stats, nullptr, nullptr, nullptr);
        bn_finalize<<<1, 256, 0, stream>>>(stats, gamma, beta, scaleC, shiftC);
        edge_gemm_fb<2><<<N_EDGES / 64, 256, 0, stream>>>(h, e, srcp, dstp, wt,
                stats, scaleC, shiftC, out);
        node_finalize<<<N_NODES * HIDDEN / (4 * 256), 256, 0, stream>>>(h, out);
    }
}

// Round 13
// 471.510 us; speedup vs baseline: 1.3177x; 1.3177x over previous
//
#include <hip/hip_runtime.h>
#include <hip/hip_bf16.h>
#include <math.h>

#define N_NODES 20000
#define N_EDGES 480000
#define HIDDEN  128
#define ZDIM    384        // 2*HIDDEN + EDGE_FEAT
#define NOUT    256        // 2*HIDDEN
#define BN_EPS  1e-5f

#define LDA     392        // fallback kernel only
#define LDZ     264        // fallback kernel only

using bf16x8 = __attribute__((ext_vector_type(8))) short;
using f32x4  = __attribute__((ext_vector_type(4))) float;
using f32x16 = __attribute__((ext_vector_type(16))) float;
using s16x4  = __attribute__((ext_vector_type(4))) short;

struct f32x8 { float4 a, b; };

__device__ __forceinline__ unsigned short f2b(float f) {
    union { float f; unsigned u; } v; v.f = f;
    unsigned r = v.u + 0x7fffu + ((v.u >> 16) & 1u);   // RTNE
    return (unsigned short)(r >> 16);
}
__device__ __forceinline__ float bflo(unsigned u) {
    union { unsigned x; float f; } v; v.x = u << 16; return v.f;
}
__device__ __forceinline__ float bfhi(unsigned u) {
    union { unsigned x; float f; } v; v.x = u & 0xffff0000u; return v.f;
}
__device__ __forceinline__ float b2f(unsigned short s) {
    union { unsigned u; float f; } v; v.u = ((unsigned)s) << 16; return v.f;
}
__device__ __forceinline__ float sigmoid_(float x) {
    return 1.f / (1.f + __expf(-x));
}
__device__ __forceinline__ float softplus_(float x) {
    return fmaxf(x, 0.f) + __logf(1.f + __expf(-fabsf(x)));
}
__device__ __forceinline__ f32x8 ld8(const float* p) {
    f32x8 r; r.a = *(const float4*)p; r.b = *(const float4*)(p + 4); return r;
}
__device__ __forceinline__ bf16x8 cvt8(f32x8 v) {
    bf16x8 pk;
    pk[0] = (short)f2b(v.a.x); pk[1] = (short)f2b(v.a.y);
    pk[2] = (short)f2b(v.a.z); pk[3] = (short)f2b(v.a.w);
    pk[4] = (short)f2b(v.b.x); pk[5] = (short)f2b(v.b.y);
    pk[6] = (short)f2b(v.b.z); pk[7] = (short)f2b(v.b.w);
    return pk;
}

// ---- W [384][256] f32  ->  Wt [256][384] bf16 ----------------------------
__global__ void convW(const float* __restrict__ W, short* __restrict__ wt) {
    int n = blockIdx.x;
    for (int k = threadIdx.x; k < ZDIM; k += 256)
        wt[n * ZDIM + k] = (short)f2b(W[(size_t)k * NOUT + n]);
}

// ---- BN stats -> scale/shift ---------------------------------------------
__global__ void bn_finalize(const float* __restrict__ stats,
                            const float* __restrict__ gamma,
                            const float* __restrict__ beta,
                            float* __restrict__ scaleC,
                            float* __restrict__ shiftC) {
    int c = threadIdx.x;
    float s = 0.f, q = 0.f;
    for (int p = 0; p < 64; ++p) {
        s += stats[p * 512 + c];
        q += stats[p * 512 + 256 + c];
    }
    const float invE = 1.f / (float)N_EDGES;
    float m   = s * invE;                    // linear bias b cancels in BN
    float var = q * invE - m * m;
    float inv = rsqrtf(var + BN_EPS);
    float sc  = gamma[c] * inv;
    scaleC[c] = sc;
    shiftC[c] = beta[c] - m * sc;
}

// ---- counting sort of edges by dst ---------------------------------------
__global__ void hist_dst(const int* __restrict__ dst, int* __restrict__ counts) {
    int i = blockIdx.x * 256 + threadIdx.x;
    if (i < N_EDGES) atomicAdd(&counts[dst[i]], 1);
}

__global__ void scan_nodes(const int* __restrict__ counts, int* __restrict__ offs,
                           int* __restrict__ cursor) {
    __shared__ int part[1024];
    int t = threadIdx.x;
    int base = t * 20;
    int local[20]; int s = 0;
    #pragma unroll
    for (int k = 0; k < 20; ++k) {
        int idx = base + k;
        int v = (idx < N_NODES) ? counts[idx] : 0;
        local[k] = s; s += v;
    }
    part[t] = s; __syncthreads();
    for (int d = 1; d < 1024; d <<= 1) {
        int v = (t >= d) ? part[t - d] : 0;
        __syncthreads();
        part[t] += v;
        __syncthreads();
    }
    int pre = (t > 0) ? part[t - 1] : 0;
    #pragma unroll
    for (int k = 0; k < 20; ++k) {
        int idx = base + k;
        if (idx < N_NODES) { int o = pre + local[k]; offs[idx] = o; cursor[idx] = o; }
    }
}

// packed per-edge info: {src, dst, dst-sorted slot, 0}
__global__ void build_einfo(const int* __restrict__ src, const int* __restrict__ dst,
                            int* __restrict__ cursor, int4* __restrict__ einfo) {
    int i = blockIdx.x * 256 + threadIdx.x;
    if (i < N_EDGES) {
        int d = dst[i];
        int slot = atomicAdd(&cursor[d], 1);
        einfo[i] = make_int4(src[i], d, slot, 0);
    }
}

// ---- node projection -> bf16, col-pair-interleaved layout ----------------
// P1[i][w*64 + l*2 + n] = bf16(h[i] @ W1[:, w*64+n*32+l]); P2 likewise for W2.
__global__ __launch_bounds__(256)
void node_proj(const float* __restrict__ h, const short* __restrict__ wt,
               unsigned short* __restrict__ P1, unsigned short* __restrict__ P2) {
    const int tid  = threadIdx.x;
    const int lane = tid & 63;
    const int l31  = lane & 31;
    const int hi   = lane >> 5;
    const int w    = tid >> 6;
    const int rowBase = blockIdx.x * 64;
    const int colBase = blockIdx.y * 256 + w * 64;   // global col 0..511

    const float* pA[2];
    #pragma unroll
    for (int mi = 0; mi < 2; ++mi) {
        int row = rowBase + mi * 32 + l31;
        if (row > N_NODES - 1) row = N_NODES - 1;
        pA[mi] = h + (size_t)row * HIDDEN + hi * 8;
    }
    const short* pB[2];
    #pragma unroll
    for (int n = 0; n < 2; ++n) {
        int c = colBase + n * 32 + l31;
        pB[n] = wt + (size_t)(c & 255) * ZDIM + (c >> 8) * 128 + hi * 8;
    }

    f32x16 acc[2][2] = {};
    #pragma unroll
    for (int kk = 0; kk < 8; ++kk) {
        bf16x8 a[2], b[2];
        #pragma unroll
        for (int mi = 0; mi < 2; ++mi) a[mi] = cvt8(ld8(pA[mi] + kk * 16));
        #pragma unroll
        for (int n = 0; n < 2; ++n) b[n] = *(const bf16x8*)(pB[n] + kk * 16);
        #pragma unroll
        for (int mi = 0; mi < 2; ++mi)
            #pragma unroll
            for (int n = 0; n < 2; ++n)
                acc[mi][n] = __builtin_amdgcn_mfma_f32_32x32x16_bf16(
                                 a[mi], b[n], acc[mi][n], 0, 0, 0);
    }

    unsigned short* Pt = (blockIdx.y == 0) ? P1 : P2;
    const int pcol = (w * 64) + l31 * 2;             // in-table interleaved idx
    #pragma unroll
    for (int mi = 0; mi < 2; ++mi)
        #pragma unroll
        for (int r = 0; r < 16; ++r) {
            int row = rowBase + mi * 32 + 4 * hi + (r & 3) + 8 * (r >> 2);
            if (row < N_NODES) {
                unsigned pk = (unsigned)f2b(acc[mi][0][r]) |
                              ((unsigned)f2b(acc[mi][1][r]) << 16);
                *(unsigned*)&Pt[(size_t)row * 256 + pcol] = pk;
            }
        }
}

// ---- per-edge GEMM: e@W3 only; packed einfo; batched phases --------------
// z stored bf16, dst-sorted, SAME pair-interleaved layout as P tables.
__global__ __launch_bounds__(256, 2)
void edge_gemm3(const float* __restrict__ e, const int4* __restrict__ einfo,
                const short* __restrict__ wt,
                const unsigned short* __restrict__ P1,
                const unsigned short* __restrict__ P2,
                float* __restrict__ stats, short* __restrict__ zout) {
    const int tid  = threadIdx.x;
    const int lane = tid & 63;
    const int l31  = lane & 31;
    const int hi   = lane >> 5;
    const int w    = tid >> 6;
    const int rowBase = blockIdx.x * 64;
    const int colBase = w * 64;
    const int pcol = colBase + l31 * 2;      // interleaved pair index

    const float* pE[2];
    #pragma unroll
    for (int mi = 0; mi < 2; ++mi)
        pE[mi] = e + (size_t)(rowBase + mi * 32 + l31) * HIDDEN + hi * 8;
    const short* pB[2];
    #pragma unroll
    for (int n = 0; n < 2; ++n)
        pB[n] = wt + (size_t)(colBase + n * 32 + l31) * ZDIM + 256 + hi * 8;

    // ---- phase 1: A batch 1 + all B loads ----
    f32x8 t[2][4];
    #pragma unroll
    for (int mi = 0; mi < 2; ++mi)
        #pragma unroll
        for (int j = 0; j < 4; ++j) t[mi][j] = ld8(pE[mi] + j * 16);
    bf16x8 B[2][8];
    #pragma unroll
    for (int n = 0; n < 2; ++n)
        #pragma unroll
        for (int kk = 0; kk < 8; ++kk)
            B[n][kk] = *(const bf16x8*)(pB[n] + kk * 16);

    bf16x8 A0[2][4], A1[2][4];
    #pragma unroll
    for (int mi = 0; mi < 2; ++mi)
        #pragma unroll
        for (int j = 0; j < 4; ++j) A0[mi][j] = cvt8(t[mi][j]);
    #pragma unroll
    for (int mi = 0; mi < 2; ++mi)
        #pragma unroll
        for (int j = 0; j < 4; ++j) t[mi][j] = ld8(pE[mi] + 64 + j * 16);

    f32x16 acc[2][2] = {};
    #pragma unroll
    for (int kk = 0; kk < 4; ++kk)
        #pragma unroll
        for (int mi = 0; mi < 2; ++mi)
            #pragma unroll
            for (int n = 0; n < 2; ++n)
                acc[mi][n] = __builtin_amdgcn_mfma_f32_32x32x16_bf16(
                                 A0[mi][kk], B[n][kk], acc[mi][n], 0, 0, 0);
    #pragma unroll
    for (int mi = 0; mi < 2; ++mi)
        #pragma unroll
        for (int j = 0; j < 4; ++j) A1[mi][j] = cvt8(t[mi][j]);
    #pragma unroll
    for (int kk = 4; kk < 8; ++kk)
        #pragma unroll
        for (int mi = 0; mi < 2; ++mi)
            #pragma unroll
            for (int n = 0; n < 2; ++n)
                acc[mi][n] = __builtin_amdgcn_mfma_f32_32x32x16_bf16(
                                 A1[mi][kk - 4], B[n][kk], acc[mi][n], 0, 0, 0);

    // ---- phase 2: packed einfo loads + P gathers ----
    unsigned ps[2][16], pd[2][16];
    int slot[2][16];
    #pragma unroll
    for (int mi = 0; mi < 2; ++mi)
        #pragma unroll
        for (int r = 0; r < 16; ++r) {
            int rowL = mi * 32 + 4 * hi + (r & 3) + 8 * (r >> 2);
            int4 ei  = einfo[rowBase + rowL];
            slot[mi][r] = ei.z;
            ps[mi][r] = *(const unsigned*)&P1[(size_t)ei.x * 256 + pcol];
            pd[mi][r] = *(const unsigned*)&P2[(size_t)ei.y * 256 + pcol];
        }

    // ---- phase 3: consume (pure VALU) + interleaved u32 store ----
    float s2[2] = {0.f, 0.f}, q2[2] = {0.f, 0.f};
    #pragma unroll
    for (int mi = 0; mi < 2; ++mi)
        #pragma unroll
        for (int r = 0; r < 16; ++r) {
            float z0 = acc[mi][0][r] + bflo(ps[mi][r]) + bflo(pd[mi][r]);
            float z1 = acc[mi][1][r] + bfhi(ps[mi][r]) + bfhi(pd[mi][r]);
            s2[0] += z0; q2[0] += z0 * z0;
            s2[1] += z1; q2[1] += z1 * z1;
            unsigned pk = (unsigned)f2b(z0) | ((unsigned)f2b(z1) << 16);
            *(unsigned*)&zout[(size_t)slot[mi][r] * NOUT + pcol] = pk;
        }
    float* base = stats + (size_t)(blockIdx.x & 63) * 512;
    #pragma unroll
    for (int n = 0; n < 2; ++n) {
        float s = s2[n], q = q2[n];
        s += __shfl_xor(s, 32, 64);
        q += __shfl_xor(q, 32, 64);
        if (lane < 32) {
            int col = colBase + n * 32 + l31;
            atomicAdd(base + col, s);
            atomicAdd(base + 256 + col, q);
        }
    }
}

// ---- fallback (small ws): stage-all-LDS GEMM, stats or scatter -----------
template<int MODE>   // 1: stats only   2: normalize+gate+atomic scatter
__global__ __launch_bounds__(256)
void edge_gemm_fb(const float* __restrict__ h, const float* __restrict__ e,
                  const int* __restrict__ src, const int* __restrict__ dst,
                  const short* __restrict__ wt,
                  float* __restrict__ stats,
                  const float* __restrict__ scaleC, const float* __restrict__ shiftC,
                  float* __restrict__ agg) {
    const int tid  = threadIdx.x;
    const int bm   = blockIdx.x;
    const int rowBase = bm * 64;
    const int lane = tid & 63;
    const int brow = lane & 15;
    const int kgo  = (lane >> 4) * 8;
    const int wcol = (tid >> 6) * 64;

    __shared__ __align__(16) short lds[64 * LDA];

    #pragma unroll
    for (int j = 0; j < 12; ++j) {
        int u = tid + j * 256;
        int r = u / 48;
        int f0 = (u - r * 48) * 8;
        int row = rowBase + r;
        const float* p;
        if (f0 < 128)      p = h + (size_t)src[row] * HIDDEN + f0;
        else if (f0 < 256) p = h + (size_t)dst[row] * HIDDEN + (f0 - 128);
        else               p = e + (size_t)row * HIDDEN + (f0 - 256);
        *(bf16x8*)&lds[r * LDA + f0] = cvt8(ld8(p));
    }
    __syncthreads();

    const short* wB[4];
    #pragma unroll
    for (int n = 0; n < 4; ++n)
        wB[n] = wt + (size_t)(wcol + n * 16 + brow) * ZDIM + kgo;

    f32x4 acc[4][4] = {};
    #pragma unroll
    for (int kk = 0; kk < 12; ++kk) {
        bf16x8 aC[4], bC[4];
        #pragma unroll
        for (int m = 0; m < 4; ++m)
            aC[m] = *(const bf16x8*)&lds[(m * 16 + brow) * LDA + kk * 32 + kgo];
        #pragma unroll
        for (int n = 0; n < 4; ++n) bC[n] = *(const bf16x8*)(wB[n] + kk * 32);
        #pragma unroll
        for (int m = 0; m < 4; ++m)
            #pragma unroll
            for (int n = 0; n < 4; ++n)
                acc[m][n] = __builtin_amdgcn_mfma_f32_16x16x32_bf16(
                                aC[m], bC[n], acc[m][n], 0, 0, 0);
    }

    if (MODE == 1) {
        float* base = stats + (size_t)(bm & 63) * 512;
        #pragma unroll
        for (int n = 0; n < 4; ++n) {
            float s = 0.f, q = 0.f;
            #pragma unroll
            for (int m = 0; m < 4; ++m)
                #pragma unroll
                for (int r = 0; r < 4; ++r) {
                    float v = acc[m][n][r]; s += v; q += v * v;
                }
            s += __shfl_xor(s, 16, 64); s += __shfl_xor(s, 32, 64);
            q += __shfl_xor(q, 16, 64); q += __shfl_xor(q, 32, 64);
            if (lane < 16) {
                int col = wcol + n * 16 + lane;
                atomicAdd(base + col, s);
                atomicAdd(base + 256 + col, q);
            }
        }
    } else {
        float sc[4], sh[4];
        #pragma unroll
        for (int n = 0; n < 4; ++n) {
            int col = wcol + n * 16 + brow;
            sc[n] = scaleC[col]; sh[n] = shiftC[col];
        }
        __syncthreads();
        #pragma unroll
        for (int m = 0; m < 4; ++m) {
            int rowb = m * 16 + (lane >> 4) * 4;
            #pragma unroll
            for (int n = 0; n < 4; ++n) {
                int col = wcol + n * 16 + brow;
                #pragma unroll
                for (int r = 0; r < 4; ++r)
                    lds[(rowb + r) * LDZ + col] = (short)f2b(acc[m][n][r] * sc[n] + sh[n]);
            }
        }
        __syncthreads();
        const int c0 = (tid & 31) * 4;
        const int r0 = tid >> 5;
        #pragma unroll
        for (int rp = 0; rp < 8; ++rp) {
            int row = rp * 8 + r0;
            int d   = dst[rowBase + row];
            float* ap = agg + (size_t)d * HIDDEN + c0;
            s16x4 f4 = *(const s16x4*)&lds[row * LDZ + c0];
            s16x4 c4 = *(const s16x4*)&lds[row * LDZ + 128 + c0];
            #pragma unroll
            for (int j = 0; j < 4; ++j)
                atomicAdd(ap + j, sigmoid_(b2f((unsigned short)f4[j])) *
                                  softplus_(b2f((unsigned short)c4[j])));
        }
    }
}

// ---- per-node gather over pair-interleaved sorted z ----------------------
// position p = 64w + 2l + n  <->  col c = 64w + 32n + l
__global__ __launch_bounds__(256)
void node_gather(const short* __restrict__ z,
                 const int* __restrict__ offs, const int* __restrict__ counts,
                 const float* __restrict__ scaleC, const float* __restrict__ shiftC,
                 const float* __restrict__ h, float* __restrict__ out) {
    int node = blockIdx.x * 4 + (threadIdx.x >> 6);
    int lane = threadIdx.x & 63;
    int l32  = lane & 31;
    const int wq = l32 >> 4;                    // 0/1
    const int c0 = 64 * wq + 2 * (l32 & 15);    // cols: c0, c0+32, c0+1, c0+33

    float scF[4], shF[4], scS[4], shS[4];
    const int cmap[4] = {c0, c0 + 32, c0 + 1, c0 + 33};
    #pragma unroll
    for (int k = 0; k < 4; ++k) {
        scF[k] = scaleC[cmap[k]];       shF[k] = shiftC[cmap[k]];
        scS[k] = scaleC[128 + cmap[k]]; shS[k] = shiftC[128 + cmap[k]];
    }

    int s   = offs[node];
    int deg = counts[node];
    float a0 = 0.f, a1 = 0.f, a2 = 0.f, a3 = 0.f;
    const int po = 4 * l32;
    const int h2 = lane >> 5;                   // even/odd slot split

    for (int j = h2; j < deg; j += 8) {
        // 4 rows in flight: j, j+2, j+4, j+6
        const short* zP[4];
        bool has[4];
        #pragma unroll
        for (int k = 0; k < 4; ++k) {
            int jk = j + 2 * k;
            has[k] = (jk < deg);
            zP[k]  = z + (size_t)(s + (has[k] ? jk : j)) * NOUT;
        }
        uint2 fv[4], cv[4];
        #pragma unroll
        for (int k = 0; k < 4; ++k) {
            fv[k] = *(const uint2*)(zP[k] + po);
            cv[k] = *(const uint2*)(zP[k] + 128 + po);
        }
        #pragma unroll
        for (int k = 0; k < 4; ++k) {
            if (has[k]) {
                float f0 = bflo(fv[k].x) * scF[0] + shF[0];
                float f1 = bfhi(fv[k].x) * scF[1] + shF[1];
                float f2 = bflo(fv[k].y) * scF[2] + shF[2];
                float f3 = bfhi(fv[k].y) * scF[3] + shF[3];
                float g0 = bflo(cv[k].x) * scS[0] + shS[0];
                float g1 = bfhi(cv[k].x) * scS[1] + shS[1];
                float g2 = bflo(cv[k].y) * scS[2] + shS[2];
                float g3 = bfhi(cv[k].y) * scS[3] + shS[3];
                a0 += sigmoid_(f0) * softplus_(g0);
                a1 += sigmoid_(f1) * softplus_(g1);
                a2 += sigmoid_(f2) * softplus_(g2);
                a3 += sigmoid_(f3) * softplus_(g3);
            }
        }
    }
    a0 += __shfl_xor(a0, 32, 64);   // col c0
    a1 += __shfl_xor(a1, 32, 64);   // col c0+32
    a2 += __shfl_xor(a2, 32, 64);   // col c0+1
    a3 += __shfl_xor(a3, 32, 64);   // col c0+33

    if (lane < 32) {
        size_t o = (size_t)node * HIDDEN;
        float2 hA = *(const float2*)&h[o + c0];
        float2 hB = *(const float2*)&h[o + c0 + 32];
        float2 rA, rB;
        rA.x = softplus_(hA.x + a0);
        rA.y = softplus_(hA.y + a2);
        rB.x = softplus_(hB.x + a1);
        rB.y = softplus_(hB.y + a3);
        *(float2*)&out[o + c0]      = rA;
        *(float2*)&out[o + c0 + 32] = rB;
    }
}

// ---- fallback finalize ----------------------------------------------------
__global__ void node_finalize(const float* __restrict__ h, float* __restrict__ out) {
    int i = blockIdx.x * 256 + threadIdx.x;
    float4 hv = ((const float4*)h)[i];
    float4 av = ((float4*)out)[i];
    float4 r;
    r.x = softplus_(hv.x + av.x);
    r.y = softplus_(hv.y + av.y);
    r.z = softplus_(hv.z + av.z);
    r.w = softplus_(hv.w + av.w);
    ((float4*)out)[i] = r;
}

extern "C" void kernel_launch(void* const* d_in, const int* in_sizes, int n_in,
                              void* d_out, int out_size, void* d_ws, size_t ws_size,
                              hipStream_t stream) {
    const float* h     = (const float*)d_in[0];
    const float* e     = (const float*)d_in[1];
    const int*   srcp  = (const int*)d_in[2];
    const int*   dstp  = (const int*)d_in[3];
    const float* W     = (const float*)d_in[4];
    // d_in[5] = b : cancels through BatchNorm
    const float* gamma = (const float*)d_in[6];
    const float* beta  = (const float*)d_in[7];
    float* out = (float*)d_out;

    char*  ws     = (char*)d_ws;
    float* stats  = (float*)ws;                        // 131072 B
    float* scaleC = (float*)(ws + 131072);
    float* shiftC = (float*)(ws + 132096);
    short* wt     = (short*)(ws + 133120);             // 192 KB -> 329728
    int*   counts = (int*)(ws + 329728);
    int*   offs   = (int*)(ws + 409856);
    int*   cursor = (int*)(ws + 489984);
    int4*  einfo  = (int4*)(ws + 570112);              // 7.68 MB -> 8250112
    unsigned short* P1 = (unsigned short*)(ws + 8250112);   // 10.24 MB
    unsigned short* P2 = (unsigned short*)(ws + 18490112);  // 10.24 MB
    short* zbuf   = (short*)(ws + 28730112);           // 245.76 MB
    const size_t need = 28730112ull + (size_t)N_EDGES * NOUT * 2;

    hipMemsetAsync(stats, 0, 131072, stream);
    convW<<<NOUT, 256, 0, stream>>>(W, wt);

    if (ws_size >= need) {
        hipMemsetAsync(counts, 0, N_NODES * sizeof(int), stream);
        hist_dst<<<(N_EDGES + 255) / 256, 256, 0, stream>>>(dstp, counts);
        scan_nodes<<<1, 1024, 0, stream>>>(counts, offs, cursor);
        build_einfo<<<(N_EDGES + 255) / 256, 256, 0, stream>>>(srcp, dstp, cursor, einfo);

        node_proj<<<dim3((N_NODES + 63) / 64, 2), 256, 0, stream>>>(h, wt, P1, P2);
        edge_gemm3<<<N_EDGES / 64, 256, 0, stream>>>(e, einfo, wt, P1, P2,
                stats, zbuf);
        bn_finalize<<<1, 256, 0, stream>>>(stats, gamma, beta, scaleC, shiftC);
        node_gather<<<N_NODES / 4, 256, 0, stream>>>(zbuf, offs, counts,
                scaleC, shiftC, h, out);
    } else {
        hipMemsetAsync(out, 0, (size_t)N_NODES * HIDDEN * sizeof(float), stream);
        edge_gemm_fb<1><<<N_EDGES / 64, 256, 0, stream>>>(h, e, srcp, dstp, wt,
                stats, nullptr, nullptr, nullptr);
        bn_finalize<<<1, 256, 0, stream>>>(stats, gamma, beta, scaleC, shiftC);
        edge_gemm_fb<2><<<N_EDGES / 64, 256, 0, stream>>>(h, e, srcp, dstp, wt,
                stats, scaleC, shiftC, out);
        node_finalize<<<N_NODES * HIDDEN / (4 * 256), 256, 0, stream>>>(h, out);
    }
}